// Round 6
// baseline (307.556 us; speedup 1.0000x reference)
//
#include <hip/hip_runtime.h>
#include <cstdint>
#include <cstddef>

// Problem constants
#define T_TOKN 16
#define NUNITS 4096
#define LPATH  32
#define NPATHS 1024
#define BNUM   8

typedef __attribute__((ext_vector_type(8))) short short8;   // 8 bf16 in 4 VGPRs
typedef __attribute__((ext_vector_type(4))) short short4x;  // 4 bf16 in 2 VGPRs
typedef __attribute__((ext_vector_type(4))) float f32x4;    // MFMA accumulator

// ws float offsets
enum : size_t {
  OFF_WFRAG   = 0,                        // 524288 ushort: lstm W frags [tf|tb|pf|pb]
  OFF_LINFRAG = 262144,                   // 65536 ushort: lin/ul B-frags
  OFF_OUTF    = 294912,                   // token fwd h, bf16 16x4096x128
  OFF_OUTB    = OFF_OUTF + 4194304,       // token bwd h (time-realigned), bf16
  OFF_OUTLIN  = OFF_OUTB + 4194304,       // bf16 16x4096x128 (intermediate only)
  OFF_SCORES  = OFF_OUTLIN + 8388608,     // f32 16x4096
  OFF_TOKFEAT = OFF_SCORES + 65536,       // f32 4096x128
  OFF_POUTF   = OFF_TOKFEAT + 524288,     // path fwd h, bf16 32x1024x128
  OFF_POUTB   = OFF_POUTF + 2097152,
  OFF_INT     = OFF_POUTB + 2097152,      // ints: tok_len 4096 | fe 1024 | p_len 1024 | off_p 1024 | un_p 1024
  WS_FLOATS   = OFF_INT + 8192
};

static __device__ __forceinline__ unsigned short f2bf(float f) {
  union { float f; unsigned u; } v; v.f = f;
  unsigned r = v.u + 0x7fffu + ((v.u >> 16) & 1u);
  return (unsigned short)(r >> 16);
}
static __device__ __forceinline__ float bf2f(unsigned short u) {
  union { unsigned u; float f; } v; v.u = ((unsigned)u) << 16;
  return v.f;
}
static __device__ __forceinline__ float sigf(float x)      { return 1.f / (1.f + __expf(-x)); }
static __device__ __forceinline__ float tanhfast(float x)  { return 2.f / (1.f + __expf(-2.f * x)) - 1.f; }

// ---------------------------------------------------------------------------
// prep (round 6: coalesced): thread = 8 consecutive k of one W row ->
// float4 x2 coalesced reads (was: 1 scalar f32/thread at lane-stride 512B,
// a 16x cacheline overfetch), aligned 16B short8 writes. Output bit layout
// IDENTICAL to r0/r5 (consumers unchanged).
//   W frag widx = (((wvp*8+ks)*4+ct)*64 + quad*16 + cl)*8 + i
//     with g = wvp*64 + ct*16 + cl, k = ks*32 + quad*8 + i
//   lin frag i2 = ((ct*8+ks)*64 + quad*16 + cl)*8 + i
//     with e = ct*16 + cl, k = ks*32 + quad*8 + i
// ---------------------------------------------------------------------------
__global__ void prep_kernel(
    const float* __restrict__ tWif, const float* __restrict__ tWhf,
    const float* __restrict__ tWib, const float* __restrict__ tWhb,
    const float* __restrict__ pWif, const float* __restrict__ pWhf,
    const float* __restrict__ pWib, const float* __restrict__ pWhb,
    const float* __restrict__ linW, const float* __restrict__ ulW,
    const int* __restrict__ units, const int* __restrict__ paths,
    const int* __restrict__ upd, const int* __restrict__ ppd,
    float* __restrict__ ws, int* __restrict__ ip)
{
  int idx = blockIdx.x * 256 + threadIdx.x;
  if (idx < 65536) {
    // ---- lstm W frags: mat(4) x g(512) x k8(32), 8 bf16 per thread ----
    unsigned short* wf = (unsigned short*)(ws + OFF_WFRAG);
    int k8 = idx & 31, g = (idx >> 5) & 511, mat = idx >> 14;
    const float* Wi; const float* Wh;
    switch (mat) {
      case 0: Wi = tWif; Wh = tWhf; break;
      case 1: Wi = tWib; Wh = tWhb; break;
      case 2: Wi = pWif; Wh = pWhf; break;
      default: Wi = pWib; Wh = pWhb; break;
    }
    int kb = k8 << 3;
    const float* sp = (kb < 128) ? (Wi + g * 128 + kb) : (Wh + g * 128 + (kb - 128));
    float4 a = *(const float4*)sp;
    float4 b = *(const float4*)(sp + 4);
    int wvp = g >> 6, ct = (g >> 4) & 3, cl = g & 15;
    int ks = k8 >> 2, quad = k8 & 3;
    size_t base = ((size_t)mat << 17) +
                  (size_t)(((((wvp * 8 + ks) * 4 + ct) * 64) + quad * 16 + cl) << 3);
    short8 o;
    o[0] = (short)f2bf(a.x); o[1] = (short)f2bf(a.y);
    o[2] = (short)f2bf(a.z); o[3] = (short)f2bf(a.w);
    o[4] = (short)f2bf(b.x); o[5] = (short)f2bf(b.y);
    o[6] = (short)f2bf(b.z); o[7] = (short)f2bf(b.w);
    *(short8*)&wf[base] = o;
  } else if (idx < 65536 + 8192) {
    // ---- lin/ul frags: mat(2) x e(128) x k8(32) ----
    unsigned short* lf = (unsigned short*)(ws + OFF_LINFRAG);
    int j = idx - 65536;
    int k8 = j & 31, e = (j >> 5) & 127, mat = j >> 12;
    const float* W = mat ? ulW : linW;
    int kb = k8 << 3;
    const float* sp = W + e * 256 + kb;
    float4 a = *(const float4*)sp;
    float4 b = *(const float4*)(sp + 4);
    int ct = e >> 4, cl = e & 15;
    int ks = k8 >> 2, quad = k8 & 3;
    size_t base = ((size_t)mat << 15) +
                  (size_t)((((ct * 8 + ks) * 64) + quad * 16 + cl) << 3);
    short8 o;
    o[0] = (short)f2bf(a.x); o[1] = (short)f2bf(a.y);
    o[2] = (short)f2bf(a.z); o[3] = (short)f2bf(a.w);
    o[4] = (short)f2bf(b.x); o[5] = (short)f2bf(b.y);
    o[6] = (short)f2bf(b.z); o[7] = (short)f2bf(b.w);
    *(short8*)&lf[base] = o;
  } else if (idx < 73728 + 4096) {
    int n = idx - 73728;
    int len = T_TOKN;
    for (int t = 0; t < T_TOKN; ++t)
      if (units[t * NUNITS + n] == 0) { len = t; break; }
    ip[n] = len;                                   // tok_len
  } else if (idx < 77824 + 1024) {
    int p = idx - 77824;
    int* fe_a  = ip + 4096;
    int* p_len = ip + 5120;
    int* off_p = ip + 6144;
    int* un_p  = ip + 7168;
    int cum = 0; int d = BNUM - 1;
    for (int dd = 0; dd < BNUM; ++dd) {
      int c2 = cum + ppd[dd];
      if (p < c2) { d = dd; break; }
      cum = c2;
    }
    int off = 0;
    for (int dd = 0; dd < d; ++dd) off += upd[dd];
    int un = upd[d];
    off_p[p] = off; un_p[p] = un;
    int f = LPATH;
    for (int t = 0; t < LPATH; ++t)
      if (paths[t * NPATHS + p] == -1) { f = t; break; }
    fe_a[p] = f;
    int pl = LPATH;
    for (int t = 0; t < LPATH; ++t) {
      int v = paths[t * NPATHS + p];
      if ((t >= f) || (v < 0) || (v > un)) { pl = t; break; }
    }
    p_len[p] = pl;
  }
}

// ---------------------------------------------------------------------------
// MFMA BiLSTM, 16-wave blocks, resident B (32 gate-cols/wave, 64 VGPR/lane).
// Round-6 delta: TRANSPOSED gates buffer gatesT[512 gates][units+pad].
// The MFMA C-layout's register axis (4 consecutive rows) is the contiguous
// axis -> acc f32x4 stores verbatim as ONE ds_write_b128 (was 16 b32), and
// PW remaps to thread=(j, 4-unit group) reading 4x ds_read_b128 (was 8 b64
// at a 4-way-conflict stride). Both sides are 2-way bank aliased (free).
// Keeps r5's idxL preload + wave-uniform dead-step skip + r0 phase order.
// MODE 0: token (emb gather, M=32), USTR=36. MODE 1: path (M=8), USTR=17,
// scalar gate access (b128 would misalign at USTR=17; inst count unchanged).
// ---------------------------------------------------------------------------
template <int MODE>
__global__ __launch_bounds__(1024, 4) void lstm_kernel(
    const unsigned short* __restrict__ wfragAll,
    const float* __restrict__ biasF, const float* __restrict__ biasB,
    const float* __restrict__ src,       // emb or tok_feat (f32)
    const int* __restrict__ idxsrc,      // units or paths
    const int* __restrict__ lens,        // tok_len or p_len
    const int* __restrict__ fe_a, const int* __restrict__ off_p, const int* __restrict__ un_p,
    unsigned short* __restrict__ outF, unsigned short* __restrict__ outB)
{
  constexpr int NN   = MODE ? NPATHS : NUNITS;
  constexpr int TT   = MODE ? LPATH : T_TOKN;
  constexpr int M    = MODE ? 8 : 32;     // real sequences per block
  constexpr int MR   = MODE ? 16 : 32;    // MFMA tile rows
  constexpr int NRT  = MR / 16;
  constexpr int ASTR = 264;               // A-tile row stride (ushorts)
  constexpr int USTR = MODE ? 17 : 36;    // gatesT unit stride (f32)

  __shared__ unsigned short ash[MR * ASTR];  // [u][0:128)=x  [u][128:256)=h
  __shared__ float gatesT[512 * USTR];       // [gate g][unit u]
  __shared__ int   idxL[M * TT];             // preloaded index columns

  int tid  = threadIdx.x;
  int dir  = blockIdx.y;
  int n0   = blockIdx.x * M;
  int lane = tid & 63, wv = tid >> 6;       // wv in [0,16)
  int cl   = lane & 15, quad = lane >> 4;

  // ---- resident B fragments: wave wv covers gates [wv*32, wv*32+32) ----
  const unsigned short* wbase =
      wfragAll + (size_t)((MODE ? 2 : 0) + dir) * 131072;
  int wv8 = wv >> 1;
  short8 bfr[8][2];
#pragma unroll
  for (int ks = 0; ks < 8; ++ks)
#pragma unroll
    for (int c2 = 0; c2 < 2; ++c2) {
      int ct = ((wv & 1) << 1) | c2;
      bfr[ks][c2] = *(const short8*)&wbase[((((wv8 * 8 + ks) * 4 + ct) * 64) + lane) * 8];
    }

  // ---- zero LDS (h region; MODE 1: whole tile incl dummy rows) ----
  if (MODE == 0) {
    for (int i = tid; i < MR * 128; i += 1024)
      ash[(i >> 7) * ASTR + 128 + (i & 127)] = 0;
  } else {
    for (int i = tid; i < MR * ASTR; i += 1024) ash[i] = 0;
  }
  // ---- preload idx columns: idxL[u*TT + t] = idxsrc[t*NN + n0+u] ----
  for (int i = tid; i < M * TT; i += 1024) {
    int u = i / TT, tt = i - u * TT;
    idxL[i] = idxsrc[tt * NN + (n0 + u)];
  }

  // ---- pointwise thread state ----
  const float* bcp = dir ? biasB : biasF;
  const int jj  = tid & 127;          // hidden column (both modes)
  const int ug  = tid >> 7;           // MODE0: 4-unit group 0..7; MODE1: unit 0..7
  float bq[4];
#pragma unroll
  for (int q = 0; q < 4; ++q) bq[q] = bcp[q * 128 + jj];
  constexpr int NU = MODE ? 1 : 4;    // units per pointwise thread
  float cst[NU];
  int   ulen[NU];
#pragma unroll
  for (int i = 0; i < NU; ++i) {
    cst[i] = 0.f;
    ulen[i] = lens[n0 + ug * NU + i];
  }

  // ---- gather thread state ----
  int gu, gk0;
  if (MODE == 0) { gu = tid >> 5; gk0 = (tid & 31) * 4; }   // 32 rows x 32 thr
  else           { gu = tid >> 7; gk0 = tid & 127; }        // 8 rows x 128 thr
  int gn = n0 + gu;
  int glen = lens[gn];
  int gfe = 0, goff = 0, gun = 0;
  if (MODE) { gfe = fe_a[gn]; goff = off_p[gn]; gun = un_p[gn]; }

  float4 xq; float xs;
  __syncthreads();   // zeros + idxL visible

  // ---- preamble: load + write x(0) ----
  {
    int tau = dir ? min(max(glen - 1, 0), TT - 1) : 0;
    int v = idxL[gu * TT + tau];
    if (MODE == 0) {
      xq = *(const float4*)&src[(size_t)v * 128 + gk0];
    } else {
      bool keep = (tau < gfe) && (v >= 0) && (v < gun);
      xs = keep ? src[(size_t)min(v + goff, NUNITS - 1) * 128 + gk0] : 0.f;
    }
  }
  if (MODE == 0) {
    short4x x4;
    x4[0] = (short)f2bf(xq.x); x4[1] = (short)f2bf(xq.y);
    x4[2] = (short)f2bf(xq.z); x4[3] = (short)f2bf(xq.w);
    *(short4x*)&ash[gu * ASTR + gk0] = x4;
  } else {
    ash[gu * ASTR + gk0] = f2bf(xs);
  }
  __syncthreads();   // x(0) visible

#pragma unroll 1
  for (int t = 0; t < TT; ++t) {
    // ===== MFMA phase (r0 ordering) =====
    {
      int tn = (t + 1 < TT) ? t + 1 : t;
      int taun = dir ? min(max(glen - 1 - tn, 0), TT - 1) : tn;
      int vn = idxL[gu * TT + taun];     // LDS read; no global idx chain
      f32x4 acc[NRT][2];
#pragma unroll
      for (int rt = 0; rt < NRT; ++rt)
#pragma unroll
        for (int c2 = 0; c2 < 2; ++c2) {
          f32x4 z = {0.f, 0.f, 0.f, 0.f};
          acc[rt][c2] = z;
        }
#pragma unroll
      for (int ks = 0; ks < 8; ++ks) {
        short8 afr[NRT];
#pragma unroll
        for (int rt = 0; rt < NRT; ++rt)
          afr[rt] = *(const short8*)&ash[(rt * 16 + cl) * ASTR + ks * 32 + (quad << 3)];
#pragma unroll
        for (int rt = 0; rt < NRT; ++rt)
#pragma unroll
          for (int c2 = 0; c2 < 2; ++c2)
            acc[rt][c2] = __builtin_amdgcn_mfma_f32_16x16x32_bf16(
                afr[rt], bfr[ks][c2], acc[rt][c2], 0, 0, 0);
      }
      // dependent x(t+1) load — latency overlaps gates-write + barrier
      if (MODE == 0) {
        xq = *(const float4*)&src[(size_t)vn * 128 + gk0];
      } else {
        bool keep = (taun < gfe) && (vn >= 0) && (vn < gun);
        xs = keep ? src[(size_t)min(vn + goff, NUNITS - 1) * 128 + gk0] : 0.f;
      }
      // preacts -> transposed gates: reg axis (4 rows) is contiguous
      if constexpr (MODE == 0) {
#pragma unroll
        for (int rt = 0; rt < NRT; ++rt)
#pragma unroll
          for (int c2 = 0; c2 < 2; ++c2) {
            int g = wv * 32 + c2 * 16 + cl;
            *(f32x4*)&gatesT[g * USTR + rt * 16 + (quad << 2)] = acc[rt][c2];
          }
      } else {
#pragma unroll
        for (int c2 = 0; c2 < 2; ++c2) {
          int g = wv * 32 + c2 * 16 + cl;
#pragma unroll
          for (int r = 0; r < 4; ++r)
            gatesT[g * USTR + (quad << 2) + r] = acc[0][c2][r];
        }
      }
    }
    __syncthreads();   // gates ready; A-tile reads done

    // ===== PW phase (wave-uniform dead-step skip) =====
    if constexpr (MODE == 0) {
      f32x4 gq0 = *(const f32x4*)&gatesT[(0 * 128 + jj) * USTR + (ug << 2)];
      f32x4 gq1 = *(const f32x4*)&gatesT[(1 * 128 + jj) * USTR + (ug << 2)];
      f32x4 gq2 = *(const f32x4*)&gatesT[(2 * 128 + jj) * USTR + (ug << 2)];
      f32x4 gq3 = *(const f32x4*)&gatesT[(3 * 128 + jj) * USTR + (ug << 2)];
#pragma unroll
      for (int r = 0; r < 4; ++r) {
        int u = (ug << 2) + r, n = n0 + u, L = ulen[r];
        if (t < L) {
          float iv = sigf(gq0[r] + bq[0]);
          float fv = sigf(gq1[r] + bq[1]);
          float gv = tanhfast(gq2[r] + bq[2]);
          float ov = sigf(gq3[r] + bq[3]);
          float c = fv * cst[r] + iv * gv;
          cst[r] = c;
          unsigned short hb = f2bf(ov * tanhfast(c));
          ash[u * ASTR + 128 + jj] = hb;
          if (dir == 0) outF[((size_t)t * NN + n) * 128 + jj] = hb;
          else          outB[((size_t)(L - 1 - t) * NN + n) * 128 + jj] = hb;
        } else {
          if (dir == 0) outF[((size_t)t * NN + n) * 128 + jj] = 0;
          else          outB[((size_t)t * NN + n) * 128 + jj] = 0;
        }
      }
    } else {
      int u = ug, n = n0 + u, L = ulen[0];
      if (t < L) {
        float p0 = gatesT[(0 * 128 + jj) * USTR + u] + bq[0];
        float p1 = gatesT[(1 * 128 + jj) * USTR + u] + bq[1];
        float p2 = gatesT[(2 * 128 + jj) * USTR + u] + bq[2];
        float p3 = gatesT[(3 * 128 + jj) * USTR + u] + bq[3];
        float ig = sigf(p0), fg = sigf(p1), gg = tanhfast(p2), og = sigf(p3);
        float c = fg * cst[0] + ig * gg;
        cst[0] = c;
        unsigned short hb = f2bf(og * tanhfast(c));
        ash[u * ASTR + 128 + jj] = hb;
        if (dir == 0) outF[((size_t)t * NN + n) * 128 + jj] = hb;
        else          outB[((size_t)(L - 1 - t) * NN + n) * 128 + jj] = hb;
      } else {
        if (dir == 0) outF[((size_t)t * NN + n) * 128 + jj] = 0;
        else          outB[((size_t)t * NN + n) * 128 + jj] = 0;
      }
    }
    // x(t+1) into A-tile (prefetched during MFMA phase)
    if (t + 1 < TT) {
      if (MODE == 0) {
        short4x x4;
        x4[0] = (short)f2bf(xq.x); x4[1] = (short)f2bf(xq.y);
        x4[2] = (short)f2bf(xq.z); x4[3] = (short)f2bf(xq.w);
        *(short4x*)&ash[gu * ASTR + gk0] = x4;
      } else {
        ash[gu * ASTR + gk0] = f2bf(xs);
      }
    }
    __syncthreads();   // h(t) + x(t+1) visible
  }
}

// ---------------------------------------------------------------------------
// MFMA GEMM: rows x 128, K=256, A = bf16 [INf|INb] from global, B resident
// (64 VGPR/lane, 4 waves cover 128 cols).  C+bias -> LDS tile -> epilogue.
// EPI 0: row-validity mask on A (invalid rows -> OUT = bias), f32 store.
// EPI 1: store OUT as BF16 (intermediate: softmax-only consumer) + fused
//        LayerNorm+tanh+attention scores.
// ---------------------------------------------------------------------------
template <int EPI>
__global__ __launch_bounds__(256) void gemm_mfma(
    const unsigned short* __restrict__ INf, const unsigned short* __restrict__ INb,
    const int* __restrict__ lens,
    const unsigned short* __restrict__ Bfrag, const float* __restrict__ bias,
    void* __restrict__ OUTv, float* __restrict__ scores,
    const float* __restrict__ lng, const float* __restrict__ lnb,
    const float* __restrict__ attw, const float* __restrict__ attb,
    const int* __restrict__ units, int Nn)
{
  constexpr int OSTR = 132;
  __shared__ float outs[64 * OSTR];
  __shared__ float red1[256];
  __shared__ float red2[256];
  __shared__ float rowm[64], rowr[64];
  __shared__ float awsh[128], lgsh[128], lbsh[128];

  int tid = threadIdx.x, lane = tid & 63, wv = tid >> 6;
  int row0 = blockIdx.x * 64;
  int t = row0 / Nn, n0 = row0 % Nn;   // 64-row blocks never straddle t

  if (EPI == 1 && tid < 128) {
    awsh[tid] = attw[tid]; lgsh[tid] = lng[tid]; lbsh[tid] = lnb[tid];
  }

  short8 bfr[8][2];
#pragma unroll
  for (int ks = 0; ks < 8; ++ks)
#pragma unroll
    for (int c2 = 0; c2 < 2; ++c2) {
      int ct = wv * 2 + c2;
      bfr[ks][c2] = *(const short8*)&Bfrag[(((ct * 8 + ks) * 64) + lane) * 8];
    }

  int rb = lane & 15;
  int koq = (lane >> 4) << 3;
  bool val[4];
#pragma unroll
  for (int rt = 0; rt < 4; ++rt)
    val[rt] = (EPI == 1) ? true : (t < lens[n0 + rt * 16 + rb]);

  f32x4 acc[4][2];
#pragma unroll
  for (int rt = 0; rt < 4; ++rt)
#pragma unroll
    for (int c2 = 0; c2 < 2; ++c2) {
      f32x4 z = {0.f, 0.f, 0.f, 0.f};
      acc[rt][c2] = z;
    }

#pragma unroll
  for (int ks = 0; ks < 8; ++ks) {
    const unsigned short* P = (ks < 4) ? INf : INb;
    int koff = (ks & 3) * 32 + koq;
#pragma unroll
    for (int rt = 0; rt < 4; ++rt) {
      short8 a = {0, 0, 0, 0, 0, 0, 0, 0};
      if (val[rt])
        a = *(const short8*)&P[((size_t)(row0 + rt * 16 + rb)) * 128 + koff];
#pragma unroll
      for (int c2 = 0; c2 < 2; ++c2)
        acc[rt][c2] = __builtin_amdgcn_mfma_f32_16x16x32_bf16(
            a, bfr[ks][c2], acc[rt][c2], 0, 0, 0);
    }
  }

  float bc[2];
#pragma unroll
  for (int c2 = 0; c2 < 2; ++c2) bc[c2] = bias[wv * 32 + c2 * 16 + rb];
#pragma unroll
  for (int rt = 0; rt < 4; ++rt)
#pragma unroll
    for (int c2 = 0; c2 < 2; ++c2) {
      int col = wv * 32 + c2 * 16 + rb;
      int ub  = rt * 16 + ((lane >> 4) << 2);
#pragma unroll
      for (int r = 0; r < 4; ++r)
        outs[(ub + r) * OSTR + col] = acc[rt][c2][r] + bc[c2];
    }
  __syncthreads();

  int row = tid >> 2, seg = tid & 3;
  const float* rp = &outs[row * OSTR + seg * 32];
  size_t go = ((size_t)(row0 + row)) * 128 + seg * 32;

  if (EPI == 0) {
    float* OUT = (float*)OUTv;
#pragma unroll
    for (int x = 0; x < 8; ++x)
      *(f32x4*)&OUT[go + x * 4] = *(const f32x4*)&rp[x * 4];
  } else {
    unsigned short* OUT = (unsigned short*)OUTv;
    f32x4 v[8];
    float s = 0.f, s2 = 0.f;
#pragma unroll
    for (int x = 0; x < 8; ++x) {
      v[x] = *(const f32x4*)&rp[x * 4];
#pragma unroll
      for (int c = 0; c < 4; ++c) { s += v[x][c]; s2 += v[x][c] * v[x][c]; }
    }
    red1[tid] = s; red2[tid] = s2;
    __syncthreads();
    if (tid < 64) {
      float a = red1[tid * 4] + red1[tid * 4 + 1] + red1[tid * 4 + 2] + red1[tid * 4 + 3];
      float b = red2[tid * 4] + red2[tid * 4 + 1] + red2[tid * 4 + 2] + red2[tid * 4 + 3];
      float m = a * (1.f / 128.f);
      float var = b * (1.f / 128.f) - m * m;
      rowm[tid] = m;
      rowr[tid] = rsqrtf(var + 1e-5f);
    }
    __syncthreads();
    float m = rowm[row], rs = rowr[row];
    float sp = 0.f;
#pragma unroll
    for (int x = 0; x < 8; ++x) {
      short4x pv;
#pragma unroll
      for (int c = 0; c < 4; ++c) {
        int col = seg * 32 + x * 4 + c;
        float q = tanhfast((v[x][c] - m) * rs * lgsh[col] + lbsh[col]);
        sp += q * awsh[col];
        pv[c] = (short)f2bf(v[x][c]);
      }
      *(short4x*)&OUT[go + x * 4] = pv;   // bf16 intermediate (8B store)
    }
    red1[tid] = sp;
    __syncthreads();
    if (tid < 64) {
      float s3 = red1[tid * 4] + red1[tid * 4 + 1] + red1[tid * 4 + 2] + red1[tid * 4 + 3]
               + attb[0];
      int n = n0 + tid;
      if (units[t * NUNITS + n] == 0) s3 = -1e9f;
      scores[t * NUNITS + n] = s3;
    }
  }
}

// ---------------------------------------------------------------------------
// Softmax over T=16 + attention-weighted pooling -> tok_feat[n][e]
// out_lin is bf16 (halved fetch).
// ---------------------------------------------------------------------------
__global__ __launch_bounds__(128) void softmax_feat_kernel(
    const float* __restrict__ scores, const unsigned short* __restrict__ out_lin,
    float* __restrict__ tok_feat)
{
  int n = blockIdx.x;
  int e = threadIdx.x;
  float s[T_TOKN];
  float m = -1e30f;
#pragma unroll
  for (int t = 0; t < T_TOKN; ++t) { s[t] = scores[t * NUNITS + n]; m = fmaxf(m, s[t]); }
  float sum = 0.f;
#pragma unroll
  for (int t = 0; t < T_TOKN; ++t) { s[t] = expf(s[t] - m); sum += s[t]; }
  float inv = 1.f / sum;
  float a = 0.f;
#pragma unroll
  for (int t = 0; t < T_TOKN; ++t)
    a += s[t] * inv * bf2f(out_lin[((size_t)t * NUNITS + n) * 128 + e]);
  tok_feat[n * 128 + e] = a;
}

// ---------------------------------------------------------------------------
extern "C" void kernel_launch(void* const* d_in, const int* in_sizes, int n_in,
                              void* d_out, int out_size, void* d_ws, size_t ws_size,
                              hipStream_t stream)
{
  const int*   units = (const int*)d_in[0];
  const int*   paths = (const int*)d_in[1];
  const int*   upd   = (const int*)d_in[2];
  const int*   ppd   = (const int*)d_in[3];
  const float* emb   = (const float*)d_in[4];
  const float* tWif  = (const float*)d_in[5];
  const float* tWhf  = (const float*)d_in[6];
  const float* tbf   = (const float*)d_in[7];
  const float* tWib  = (const float*)d_in[8];
  const float* tWhb  = (const float*)d_in[9];
  const float* tbb   = (const float*)d_in[10];
  const float* linW  = (const float*)d_in[11];
  const float* linb  = (const float*)d_in[12];
  const float* lng   = (const float*)d_in[13];
  const float* lnb   = (const float*)d_in[14];
  const float* attw  = (const float*)d_in[15];
  const float* attb  = (const float*)d_in[16];
  const float* pWif  = (const float*)d_in[17];
  const float* pWhf  = (const float*)d_in[18];
  const float* pbf   = (const float*)d_in[19];
  const float* pWib  = (const float*)d_in[20];
  const float* pWhb  = (const float*)d_in[21];
  const float* pbb   = (const float*)d_in[22];
  const float* ulW   = (const float*)d_in[23];
  const float* ulb   = (const float*)d_in[24];

  float* ws = (float*)d_ws;
  int*   ip = (int*)(ws + OFF_INT);
  if (ws_size < WS_FLOATS * sizeof(float)) return;

  unsigned short* wfrag   = (unsigned short*)(ws + OFF_WFRAG);
  unsigned short* linfrag = (unsigned short*)(ws + OFF_LINFRAG);
  unsigned short* ulfrag  = linfrag + 32768;
  unsigned short* OUTF  = (unsigned short*)(ws + OFF_OUTF);
  unsigned short* OUTB  = (unsigned short*)(ws + OFF_OUTB);
  unsigned short* POUTF = (unsigned short*)(ws + OFF_POUTF);
  unsigned short* POUTB = (unsigned short*)(ws + OFF_POUTB);

  prep_kernel<<<308, 256, 0, stream>>>(tWif, tWhf, tWib, tWhb,
                                       pWif, pWhf, pWib, pWhb,
                                       linW, ulW, units, paths, upd, ppd,
                                       ws, ip);

  lstm_kernel<0><<<dim3(128, 2), 1024, 0, stream>>>(
      wfrag, tbf, tbb, emb, units, ip /*tok_len*/, nullptr, nullptr, nullptr,
      OUTF, OUTB);

  gemm_mfma<1><<<1024, 256, 0, stream>>>(
      OUTF, OUTB, ip /*tok_len*/, linfrag, linb,
      (void*)(ws + OFF_OUTLIN), ws + OFF_SCORES, lng, lnb, attw, attb, units, NUNITS);

  softmax_feat_kernel<<<4096, 128, 0, stream>>>(
      ws + OFF_SCORES, (const unsigned short*)(ws + OFF_OUTLIN),
      ws + OFF_TOKFEAT);

  lstm_kernel<1><<<dim3(128, 2), 1024, 0, stream>>>(
      wfrag, pbf, pbb, ws + OFF_TOKFEAT, paths, ip + 5120 /*p_len*/,
      ip + 4096 /*fe*/, ip + 6144 /*off_p*/, ip + 7168 /*un_p*/,
      POUTF, POUTB);

  gemm_mfma<0><<<512, 256, 0, stream>>>(
      POUTF, POUTB, ip + 5120 /*p_len*/, ulfrag, ulb,
      (void*)d_out, nullptr, nullptr, nullptr, nullptr, nullptr, nullptr, NPATHS);
}